// Round 5
// baseline (229.287 us; speedup 1.0000x reference)
//
#include <hip/hip_runtime.h>

// SimCLR fused pipeline, round 5: both GEMMs on MFMA via bf16x2 (Dekker split,
// fp32-grade accuracy), BN stats fused into gemm1 epilogue (atomics), sim with
// unrolled double-buffer + maskless diag (subtracted in row_finalize), loss
// reduced via atomics. No LDS staging anywhere - all MFMA frags load directly
// from global (everything is L2-resident).

#define NB   4096
#define DIN  192
#define DHID 512
#define DOUT 128
#define N2   8192   // 2*NB
#define NSPLIT 32   // sim col-splits; 256 cols per block

typedef short short8 __attribute__((ext_vector_type(8)));   // 8 bf16 (4 VGPRs)
typedef float floatx4 __attribute__((ext_vector_type(4)));  // MFMA C/D frag

// Truncation-based Dekker split: x ~= hi + lo with |err| < 2^-16 |x|.
__device__ inline void split8(const float* x, short8& hi, short8& lo) {
    #pragma unroll
    for (int j = 0; j < 8; ++j) {
        unsigned int u = __float_as_uint(x[j]);
        float hf = __uint_as_float(u & 0xffff0000u);
        float r = x[j] - hf;                       // exact
        hi[j] = (short)(u >> 16);
        lo[j] = (short)(__float_as_uint(r) >> 16);
    }
}

__device__ inline unsigned short bf16_rne(float x) {
    unsigned int u = __float_as_uint(x);
    return (unsigned short)((u + 0x7fffu + ((u >> 16) & 1u)) >> 16);
}

// ---------------- convert W1, W2 -> hi/lo bf16 ------------------------------
__global__ __launch_bounds__(256) void convert_w(
    const float* __restrict__ W1, const float* __restrict__ W2,
    unsigned short* __restrict__ W1hi, unsigned short* __restrict__ W1lo,
    unsigned short* __restrict__ W2hi, unsigned short* __restrict__ W2lo)
{
    const int NW1 = DHID * DIN / 4;   // 24576 float4
    const int NW2 = DOUT * DHID / 4;  // 16384 float4
    int id = blockIdx.x * 256 + threadIdx.x;
    const float* src; unsigned short *dh, *dl; int off;
    if (id < NW1)            { src = W1; dh = W1hi; dl = W1lo; off = id; }
    else if (id < NW1 + NW2) { src = W2; dh = W2hi; dl = W2lo; off = id - NW1; }
    else return;
    float4 x = ((const float4*)src)[off];
    float xs[4] = {x.x, x.y, x.z, x.w};
    unsigned int hp[2], lp[2];
    #pragma unroll
    for (int p = 0; p < 2; ++p) {
        unsigned int u0 = __float_as_uint(xs[p*2]);
        unsigned int u1 = __float_as_uint(xs[p*2+1]);
        float r0 = xs[p*2]   - __uint_as_float(u0 & 0xffff0000u);
        float r1 = xs[p*2+1] - __uint_as_float(u1 & 0xffff0000u);
        hp[p] = (u0 >> 16) | (u1 & 0xffff0000u);
        lp[p] = (__float_as_uint(r0) >> 16) | (__float_as_uint(r1) & 0xffff0000u);
    }
    ((uint2*)dh)[off] = make_uint2(hp[0], hp[1]);
    ((uint2*)dl)[off] = make_uint2(lp[0], lp[1]);
}

// ------- GEMM1 (MFMA bf16x2): Y = [h1;h2] @ W1^T + b1, fused BN col-sums ---
// grid (64 m-blocks of 128 rows, 8 n-splits of 64 cols), 256 thr (4 waves).
// Wave: 32 rows (2 m-tiles) x 64 cols (4 n-tiles), K=192 (6 kc).
__global__ __launch_bounds__(256) void gemm1_mfma(
    const float* __restrict__ h1, const float* __restrict__ h2,
    const unsigned short* __restrict__ W1hi, const unsigned short* __restrict__ W1lo,
    const float* __restrict__ b1,
    float* __restrict__ Y, float* __restrict__ psumc, float* __restrict__ psqc)
{
    const int t = threadIdx.x;
    const int wave = t >> 6, lane = t & 63;
    const int quad = lane >> 4, l15 = lane & 15;
    const int mb = blockIdx.x;
    const int m0 = mb * 128 + wave * 32;
    const int n0 = blockIdx.y * 64;
    const int v  = (mb >= 32);

    // A: load h fp32, split -> hi/lo frags. 2 m-tiles x 6 kc.
    short8 ahi[2][6], alo[2][6];
    #pragma unroll
    for (int mt = 0; mt < 2; ++mt) {
        int row = m0 + mt * 16 + l15;
        const float* hsrc = (row < NB) ? (h1 + (size_t)row * DIN)
                                       : (h2 + (size_t)(row - NB) * DIN);
        #pragma unroll
        for (int kc = 0; kc < 6; ++kc) {
            const float4* p = (const float4*)(hsrc + kc * 32 + quad * 8);
            float4 x0 = p[0], x1 = p[1];
            float xs[8] = {x0.x,x0.y,x0.z,x0.w,x1.x,x1.y,x1.z,x1.w};
            split8(xs, ahi[mt][kc], alo[mt][kc]);
        }
    }

    #pragma unroll
    for (int nt = 0; nt < 4; ++nt) {
        const int col = n0 + nt * 16 + l15;
        const short8* bh = (const short8*)(W1hi + (size_t)col * DIN + quad * 8);
        const short8* bl = (const short8*)(W1lo + (size_t)col * DIN + quad * 8);
        short8 bhi[6], blo[6];
        #pragma unroll
        for (int kc = 0; kc < 6; ++kc) { bhi[kc] = bh[kc * 4]; blo[kc] = bl[kc * 4]; }
        floatx4 acc[2] = {{0.f,0.f,0.f,0.f},{0.f,0.f,0.f,0.f}};
        #pragma unroll
        for (int kc = 0; kc < 6; ++kc)
            #pragma unroll
            for (int mt = 0; mt < 2; ++mt) {
                acc[mt] = __builtin_amdgcn_mfma_f32_16x16x32_bf16(alo[mt][kc], bhi[kc], acc[mt], 0,0,0);
                acc[mt] = __builtin_amdgcn_mfma_f32_16x16x32_bf16(ahi[mt][kc], blo[kc], acc[mt], 0,0,0);
                acc[mt] = __builtin_amdgcn_mfma_f32_16x16x32_bf16(ahi[mt][kc], bhi[kc], acc[mt], 0,0,0);
            }
        const float bias = b1[col];
        float cs = 0.f, cq = 0.f;
        #pragma unroll
        for (int mt = 0; mt < 2; ++mt)
            #pragma unroll
            for (int reg = 0; reg < 4; ++reg) {
                float y = acc[mt][reg] + bias;
                int row = m0 + mt * 16 + quad * 4 + reg;
                Y[(size_t)row * DHID + col] = y;
                cs += y; cq += y * y;
            }
        cs += __shfl_xor(cs, 16); cs += __shfl_xor(cs, 32);
        cq += __shfl_xor(cq, 16); cq += __shfl_xor(cq, 32);
        if (quad == 0) {
            atomicAdd(psumc + v * DHID + col, cs);
            atomicAdd(psqc  + v * DHID + col, cq);
        }
    }
}

// ---------------- BN finalize: mean/var -> fused scale/shift ----------------
__global__ __launch_bounds__(256) void bn_stats_final(
    const float* __restrict__ psumc, const float* __restrict__ psqc,
    const float* __restrict__ gamma, const float* __restrict__ beta,
    float* __restrict__ bnscale, float* __restrict__ bnshift)
{
    int id = blockIdx.x * 256 + threadIdx.x;   // 0..1023
    int c = id & 511;
    float mean = psumc[id] * (1.0f / NB);
    float var  = psqc[id] * (1.0f / NB) - mean * mean;
    float rstd = rsqrtf(var + 1e-5f);
    float sc = gamma[c] * rstd;
    bnscale[id] = sc;
    bnshift[id] = beta[c] - mean * sc;
}

#define ZSCALE 1.6986436f   // sqrt(2*log2(e)); Zb = z*ZSCALE so dot = exp2 arg

// ---- GEMM2 (MFMA bf16x2): z = relu(bn(Y)) @ W2^T + b2, L2-norm ------------
// grid 256 blocks x 128 thr (2 waves); wave = 16 rows, all 128 cols, K=512.
__global__ __launch_bounds__(128) void gemm2_mfma(
    const float* __restrict__ Y,
    const unsigned short* __restrict__ W2hi, const unsigned short* __restrict__ W2lo,
    const float* __restrict__ bnscale, const float* __restrict__ bnshift,
    const float* __restrict__ b2,
    unsigned short* __restrict__ Zb, float* __restrict__ outz)
{
    const int t = threadIdx.x;
    const int wave = t >> 6, lane = t & 63;
    const int quad = lane >> 4, l15 = lane & 15;
    const int mtbase = blockIdx.x * 32 + wave * 16;
    const int arow = mtbase + l15;            // A-operand row for this lane
    const int v = (mtbase >= NB);
    const float* sc = bnscale + v * DHID;
    const float* sh = bnshift + v * DHID;
    const float* yrow = Y + (size_t)arow * DHID;

    floatx4 acc[8] = {{0.f,0.f,0.f,0.f},{0.f,0.f,0.f,0.f},{0.f,0.f,0.f,0.f},{0.f,0.f,0.f,0.f},
                      {0.f,0.f,0.f,0.f},{0.f,0.f,0.f,0.f},{0.f,0.f,0.f,0.f},{0.f,0.f,0.f,0.f}};
    for (int kc = 0; kc < 16; ++kc) {
        const int k = kc * 32 + quad * 8;
        float4 y0 = *(const float4*)(yrow + k);
        float4 y1 = *(const float4*)(yrow + k + 4);
        float4 s0 = *(const float4*)(sc + k), s1 = *(const float4*)(sc + k + 4);
        float4 h0 = *(const float4*)(sh + k), h1v = *(const float4*)(sh + k + 4);
        float xs[8];
        xs[0] = fmaxf(y0.x * s0.x + h0.x, 0.f);
        xs[1] = fmaxf(y0.y * s0.y + h0.y, 0.f);
        xs[2] = fmaxf(y0.z * s0.z + h0.z, 0.f);
        xs[3] = fmaxf(y0.w * s0.w + h0.w, 0.f);
        xs[4] = fmaxf(y1.x * s1.x + h1v.x, 0.f);
        xs[5] = fmaxf(y1.y * s1.y + h1v.y, 0.f);
        xs[6] = fmaxf(y1.z * s1.z + h1v.z, 0.f);
        xs[7] = fmaxf(y1.w * s1.w + h1v.w, 0.f);
        short8 ahi, alo;
        split8(xs, ahi, alo);
        #pragma unroll
        for (int nt = 0; nt < 8; ++nt) {
            const size_t colk = (size_t)(nt * 16 + l15) * DHID + k;
            short8 bh = *(const short8*)(W2hi + colk);
            short8 bl = *(const short8*)(W2lo + colk);
            acc[nt] = __builtin_amdgcn_mfma_f32_16x16x32_bf16(alo, bh, acc[nt], 0,0,0);
            acc[nt] = __builtin_amdgcn_mfma_f32_16x16x32_bf16(ahi, bl, acc[nt], 0,0,0);
            acc[nt] = __builtin_amdgcn_mfma_f32_16x16x32_bf16(ahi, bh, acc[nt], 0,0,0);
        }
    }
    float bias[8];
    #pragma unroll
    for (int nt = 0; nt < 8; ++nt) bias[nt] = b2[nt * 16 + l15];
    #pragma unroll
    for (int reg = 0; reg < 4; ++reg) {
        float zv[8]; float sq = 0.f;
        #pragma unroll
        for (int nt = 0; nt < 8; ++nt) {
            zv[nt] = acc[nt][reg] + bias[nt];
            sq += zv[nt] * zv[nt];
        }
        sq += __shfl_xor(sq, 1); sq += __shfl_xor(sq, 2);
        sq += __shfl_xor(sq, 4); sq += __shfl_xor(sq, 8);
        float inv = 1.0f / fmaxf(sqrtf(sq), 1e-12f);
        const int orow = mtbase + quad * 4 + reg;
        const size_t ob = (size_t)orow * DOUT;
        #pragma unroll
        for (int nt = 0; nt < 8; ++nt) {
            float z = zv[nt] * inv;
            outz[ob + nt * 16 + l15] = z;
            Zb[ob + nt * 16 + l15] = bf16_rne(z * ZSCALE);
        }
    }
}

// ---- sim: psum_row = sum_cols exp2(Zb . Zb^T)  (diag INCLUDED; subtracted
// later). Wave: 64 rows (4 A-tiles). 8 groups of 32 cols, fully unrolled
// alternating double-buffer prefetch. grid (32, NSPLIT), 256 thr.
__global__ __launch_bounds__(256) void sim_mfma(
    const unsigned short* __restrict__ Zb, float* __restrict__ psum)
{
    const int t = threadIdx.x;
    const int wave = t >> 6, lane = t & 63;
    const int quad = lane >> 4, l15 = lane & 15;
    const int mbase = blockIdx.x * 256 + wave * 64;
    const int cs = blockIdx.y;
    const int cbase = cs * (N2 / NSPLIT);   // 256-col slice

    short8 a[4][4];
    #pragma unroll
    for (int at = 0; at < 4; ++at) {
        const short8* zra = (const short8*)(Zb + (size_t)(mbase + at * 16 + l15) * DOUT + quad * 8);
        #pragma unroll
        for (int kc = 0; kc < 4; ++kc) a[at][kc] = zra[kc * 4];
    }

    float rs[4][4];
    #pragma unroll
    for (int at = 0; at < 4; ++at)
        #pragma unroll
        for (int r = 0; r < 4; ++r) rs[at][r] = 0.f;

    short8 b[2][8];   // [buf][half*4 + kc], 32 cols per buffer
    #pragma unroll
    for (int half = 0; half < 2; ++half) {
        const short8* zb = (const short8*)(Zb + (size_t)(cbase + half * 16 + l15) * DOUT + quad * 8);
        #pragma unroll
        for (int kc = 0; kc < 4; ++kc) b[0][half * 4 + kc] = zb[kc * 4];
    }

    #pragma unroll
    for (int g = 0; g < 8; ++g) {         // 8 groups of 32 cols, unrolled
        const int cur = g & 1, nxt = cur ^ 1;
        const int gc = cbase + ((g + 1) & 7) * 32;   // prefetch (wraps, unused)
        #pragma unroll
        for (int half = 0; half < 2; ++half) {
            const short8* zb = (const short8*)(Zb + (size_t)(gc + half * 16 + l15) * DOUT + quad * 8);
            #pragma unroll
            for (int kc = 0; kc < 4; ++kc) b[nxt][half * 4 + kc] = zb[kc * 4];
        }
        #pragma unroll
        for (int half = 0; half < 2; ++half) {
            floatx4 acc[4] = {{0.f,0.f,0.f,0.f},{0.f,0.f,0.f,0.f},
                              {0.f,0.f,0.f,0.f},{0.f,0.f,0.f,0.f}};
            #pragma unroll
            for (int kc = 0; kc < 4; ++kc)
                #pragma unroll
                for (int at = 0; at < 4; ++at)
                    acc[at] = __builtin_amdgcn_mfma_f32_16x16x32_bf16(
                        a[at][kc], b[cur][half * 4 + kc], acc[at], 0,0,0);
            #pragma unroll
            for (int at = 0; at < 4; ++at)
                #pragma unroll
                for (int r = 0; r < 4; ++r)
                    rs[at][r] += exp2f(acc[at][r]);
        }
    }

    #pragma unroll
    for (int at = 0; at < 4; ++at) {
        const int gi0 = mbase + at * 16 + quad * 4;
        #pragma unroll
        for (int r = 0; r < 4; ++r) {
            float s = rs[at][r];
            s += __shfl_xor(s, 1); s += __shfl_xor(s, 2);
            s += __shfl_xor(s, 4); s += __shfl_xor(s, 8);
            if (l15 == 0) psum[(size_t)cs * N2 + gi0 + r] = s;
        }
    }
}

// ---- per-row lse - pos, minus diag term; block-reduce -> atomic loss ------
__global__ __launch_bounds__(256) void row_finalize(
    const unsigned short* __restrict__ Zb, const float* __restrict__ psum,
    float* __restrict__ out)
{
    int i = blockIdx.x * 256 + threadIdx.x;
    float s = 0.f;
    #pragma unroll
    for (int cs = 0; cs < NSPLIT; ++cs) s += psum[(size_t)cs * N2 + i];
    int k = i & (NB - 1);
    const uint4* z1 = (const uint4*)(Zb + (size_t)k * DOUT);
    const uint4* z2 = (const uint4*)(Zb + (size_t)(k + NB) * DOUT);
    float d12 = 0.f, d11 = 0.f, d22 = 0.f;
    #pragma unroll
    for (int q = 0; q < 16; ++q) {
        uint4 a = z1[q], bqq = z2[q];
        const unsigned int aw[4] = {a.x, a.y, a.z, a.w};
        const unsigned int bw[4] = {bqq.x, bqq.y, bqq.z, bqq.w};
        #pragma unroll
        for (int c = 0; c < 4; ++c) {
            float alo = __uint_as_float(aw[c] << 16);
            float ahi = __uint_as_float(aw[c] & 0xffff0000u);
            float blo = __uint_as_float(bw[c] << 16);
            float bhi = __uint_as_float(bw[c] & 0xffff0000u);
            d12 += alo * blo + ahi * bhi;
            d11 += alo * alo + ahi * ahi;
            d22 += blo * blo + bhi * bhi;
        }
    }
    float dself = (i < NB) ? d11 : d22;
    // Zb is scaled: dot' = 2*log2(e)*dot  =>  2*dot = dot'*ln2; diag = exp2(dot')
    float rowval = logf(s - exp2f(dself)) - d12 * 0.69314718f;

    // block reduction -> one atomic
    float r = rowval;
    r += __shfl_xor(r, 1);  r += __shfl_xor(r, 2);  r += __shfl_xor(r, 4);
    r += __shfl_xor(r, 8);  r += __shfl_xor(r, 16); r += __shfl_xor(r, 32);
    __shared__ float wsr[4];
    int lane = threadIdx.x & 63, w = threadIdx.x >> 6;
    if (lane == 0) wsr[w] = r;
    __syncthreads();
    if (threadIdx.x == 0)
        atomicAdd(out, (wsr[0] + wsr[1] + wsr[2] + wsr[3]) * (1.0f / N2));
}

extern "C" void kernel_launch(void* const* d_in, const int* in_sizes, int n_in,
                              void* d_out, int out_size, void* d_ws, size_t ws_size,
                              hipStream_t stream)
{
    const float* h1    = (const float*)d_in[0];
    const float* h2    = (const float*)d_in[1];
    const float* W1    = (const float*)d_in[2];
    const float* b1    = (const float*)d_in[3];
    const float* gamma = (const float*)d_in[4];
    const float* beta  = (const float*)d_in[5];
    const float* W2    = (const float*)d_in[6];
    const float* b2    = (const float*)d_in[7];
    float* out = (float*)d_out;

    float* ws      = (float*)d_ws;
    float* psumc   = ws;                            // 1024 f
    float* psqc    = psumc + 1024;                  // 1024 f
    float* bnscale = psqc + 1024;                   // 1024 f
    float* bnshift = bnscale + 1024;                // 1024 f
    unsigned short* W1hi = (unsigned short*)(bnshift + 1024);  // 98304 us = 49152 f
    unsigned short* W1lo = W1hi + DHID * DIN;
    unsigned short* W2hi = W1lo + DHID * DIN;       // 65536 us = 32768 f
    unsigned short* W2lo = W2hi + DOUT * DHID;
    float* Y       = (float*)(W2lo + DOUT * DHID);  // 8192*512 = 4M f
    float* psum    = Y + (size_t)N2 * DHID;         // 32*8192 = 262144 f
    unsigned short* Zb = (unsigned short*)(psum + (size_t)NSPLIT * N2); // 1M us
    // total ~19.4 MB

    hipMemsetAsync(psumc, 0, 2048 * sizeof(float), stream);  // psumc+psqc
    hipMemsetAsync(out, 0, sizeof(float), stream);           // loss accumulator

    convert_w     <<<dim3(160),     256, 0, stream>>>(W1, W2, W1hi, W1lo, W2hi, W2lo);
    gemm1_mfma    <<<dim3(64, 8),   256, 0, stream>>>(h1, h2, W1hi, W1lo, b1, Y, psumc, psqc);
    bn_stats_final<<<dim3(4),       256, 0, stream>>>(psumc, psqc, gamma, beta, bnscale, bnshift);
    gemm2_mfma    <<<dim3(256),     128, 0, stream>>>(Y, W2hi, W2lo, bnscale, bnshift, b2, Zb, out + 1);
    sim_mfma      <<<dim3(32, NSPLIT), 256, 0, stream>>>(Zb, psum);
    row_finalize  <<<dim3(32),      256, 0, stream>>>(Zb, psum, out);
}

// Round 6
// 193.900 us; speedup vs baseline: 1.1825x; 1.1825x over previous
//
#include <hip/hip_runtime.h>

// SimCLR fused pipeline, round 6.
// sim: 64 rows/wave, 16-col stages, 3-buffer prefetch-distance-2 rotation
//      (register-lean: b[3][4]=48 VGPRs vs round-5's 64+) — fixes the
//      round-5 occupancy cliff (VGPR 196 -> ~160).
// gemm2: N-split x2 (1024 waves), bn-finalize fused in via LDS.
// gemm1: MFMA bf16x2 with fused BN col-sum atomics (unchanged from r5).

#define NB   4096
#define DIN  192
#define DHID 512
#define DOUT 128
#define N2   8192   // 2*NB
#define NSPLIT 32   // sim col-splits; 256 cols per block

typedef short short8 __attribute__((ext_vector_type(8)));   // 8 bf16 (4 VGPRs)
typedef float floatx4 __attribute__((ext_vector_type(4)));  // MFMA C/D frag

// Truncation-based Dekker split: x ~= hi + lo with |err| < 2^-16 |x|.
__device__ inline void split8(const float* x, short8& hi, short8& lo) {
    #pragma unroll
    for (int j = 0; j < 8; ++j) {
        unsigned int u = __float_as_uint(x[j]);
        float hf = __uint_as_float(u & 0xffff0000u);
        float r = x[j] - hf;                       // exact
        hi[j] = (short)(u >> 16);
        lo[j] = (short)(__float_as_uint(r) >> 16);
    }
}

__device__ inline unsigned short bf16_rne(float x) {
    unsigned int u = __float_as_uint(x);
    return (unsigned short)((u + 0x7fffu + ((u >> 16) & 1u)) >> 16);
}

// ---------------- convert W1, W2 -> hi/lo bf16 ------------------------------
__global__ __launch_bounds__(256) void convert_w(
    const float* __restrict__ W1, const float* __restrict__ W2,
    unsigned short* __restrict__ W1hi, unsigned short* __restrict__ W1lo,
    unsigned short* __restrict__ W2hi, unsigned short* __restrict__ W2lo)
{
    const int NW1 = DHID * DIN / 4;   // 24576 float4
    const int NW2 = DOUT * DHID / 4;  // 16384 float4
    int id = blockIdx.x * 256 + threadIdx.x;
    const float* src; unsigned short *dh, *dl; int off;
    if (id < NW1)            { src = W1; dh = W1hi; dl = W1lo; off = id; }
    else if (id < NW1 + NW2) { src = W2; dh = W2hi; dl = W2lo; off = id - NW1; }
    else return;
    float4 x = ((const float4*)src)[off];
    float xs[4] = {x.x, x.y, x.z, x.w};
    unsigned int hp[2], lp[2];
    #pragma unroll
    for (int p = 0; p < 2; ++p) {
        unsigned int u0 = __float_as_uint(xs[p*2]);
        unsigned int u1 = __float_as_uint(xs[p*2+1]);
        float r0 = xs[p*2]   - __uint_as_float(u0 & 0xffff0000u);
        float r1 = xs[p*2+1] - __uint_as_float(u1 & 0xffff0000u);
        hp[p] = (u0 >> 16) | (u1 & 0xffff0000u);
        lp[p] = (__float_as_uint(r0) >> 16) | (__float_as_uint(r1) & 0xffff0000u);
    }
    ((uint2*)dh)[off] = make_uint2(hp[0], hp[1]);
    ((uint2*)dl)[off] = make_uint2(lp[0], lp[1]);
}

// ------- GEMM1 (MFMA bf16x2): Y = [h1;h2] @ W1^T + b1, fused BN col-sums ---
// grid (64 m-blocks of 128 rows, 8 n-splits of 64 cols), 256 thr (4 waves).
__global__ __launch_bounds__(256) void gemm1_mfma(
    const float* __restrict__ h1, const float* __restrict__ h2,
    const unsigned short* __restrict__ W1hi, const unsigned short* __restrict__ W1lo,
    const float* __restrict__ b1,
    float* __restrict__ Y, float* __restrict__ psumc, float* __restrict__ psqc)
{
    const int t = threadIdx.x;
    const int wave = t >> 6, lane = t & 63;
    const int quad = lane >> 4, l15 = lane & 15;
    const int mb = blockIdx.x;
    const int m0 = mb * 128 + wave * 32;
    const int n0 = blockIdx.y * 64;
    const int v  = (mb >= 32);

    short8 ahi[2][6], alo[2][6];
    #pragma unroll
    for (int mt = 0; mt < 2; ++mt) {
        int row = m0 + mt * 16 + l15;
        const float* hsrc = (row < NB) ? (h1 + (size_t)row * DIN)
                                       : (h2 + (size_t)(row - NB) * DIN);
        #pragma unroll
        for (int kc = 0; kc < 6; ++kc) {
            const float4* p = (const float4*)(hsrc + kc * 32 + quad * 8);
            float4 x0 = p[0], x1 = p[1];
            float xs[8] = {x0.x,x0.y,x0.z,x0.w,x1.x,x1.y,x1.z,x1.w};
            split8(xs, ahi[mt][kc], alo[mt][kc]);
        }
    }

    #pragma unroll
    for (int nt = 0; nt < 4; ++nt) {
        const int col = n0 + nt * 16 + l15;
        const short8* bh = (const short8*)(W1hi + (size_t)col * DIN + quad * 8);
        const short8* bl = (const short8*)(W1lo + (size_t)col * DIN + quad * 8);
        short8 bhi[6], blo[6];
        #pragma unroll
        for (int kc = 0; kc < 6; ++kc) { bhi[kc] = bh[kc * 4]; blo[kc] = bl[kc * 4]; }
        floatx4 acc[2] = {{0.f,0.f,0.f,0.f},{0.f,0.f,0.f,0.f}};
        #pragma unroll
        for (int kc = 0; kc < 6; ++kc)
            #pragma unroll
            for (int mt = 0; mt < 2; ++mt) {
                acc[mt] = __builtin_amdgcn_mfma_f32_16x16x32_bf16(alo[mt][kc], bhi[kc], acc[mt], 0,0,0);
                acc[mt] = __builtin_amdgcn_mfma_f32_16x16x32_bf16(ahi[mt][kc], blo[kc], acc[mt], 0,0,0);
                acc[mt] = __builtin_amdgcn_mfma_f32_16x16x32_bf16(ahi[mt][kc], bhi[kc], acc[mt], 0,0,0);
            }
        const float bias = b1[col];
        float cs = 0.f, cq = 0.f;
        #pragma unroll
        for (int mt = 0; mt < 2; ++mt)
            #pragma unroll
            for (int reg = 0; reg < 4; ++reg) {
                float y = acc[mt][reg] + bias;
                int row = m0 + mt * 16 + quad * 4 + reg;
                Y[(size_t)row * DHID + col] = y;
                cs += y; cq += y * y;
            }
        cs += __shfl_xor(cs, 16); cs += __shfl_xor(cs, 32);
        cq += __shfl_xor(cq, 16); cq += __shfl_xor(cq, 32);
        if (quad == 0) {
            atomicAdd(psumc + v * DHID + col, cs);
            atomicAdd(psqc  + v * DHID + col, cq);
        }
    }
}

#define ZSCALE 1.6986436f   // sqrt(2*log2(e)); Zb = z*ZSCALE so dot = exp2 arg

// ---- GEMM2 (MFMA bf16x2): z = relu(bn(Y)) @ W2^T + b2, L2-norm ------------
// bn-finalize fused (per-block, into LDS). N-split x2: wave = 16 rows x 64
// cols, K=512; wave-pair combines row-sq via LDS. grid 512 x 128 thr.
__global__ __launch_bounds__(128) void gemm2_mfma(
    const float* __restrict__ Y,
    const unsigned short* __restrict__ W2hi, const unsigned short* __restrict__ W2lo,
    const float* __restrict__ psumc, const float* __restrict__ psqc,
    const float* __restrict__ gamma, const float* __restrict__ beta,
    const float* __restrict__ b2,
    unsigned short* __restrict__ Zb, float* __restrict__ outz)
{
    __shared__ float sc_sh[DHID], sh_sh[DHID];
    __shared__ float sq_lds[2][16];
    const int t = threadIdx.x;
    const int wave = t >> 6, lane = t & 63;
    const int quad = lane >> 4, l15 = lane & 15;
    const int mtbase = blockIdx.x * 16;
    const int v = (mtbase >= NB);

    for (int c = t; c < DHID; c += 128) {
        float mean = psumc[v * DHID + c] * (1.0f / NB);
        float var  = psqc [v * DHID + c] * (1.0f / NB) - mean * mean;
        float rstd = rsqrtf(var + 1e-5f);
        float scv = gamma[c] * rstd;
        sc_sh[c] = scv;
        sh_sh[c] = beta[c] - mean * scv;
    }
    __syncthreads();

    const float* yrow = Y + (size_t)(mtbase + l15) * DHID;
    floatx4 acc[4] = {{0.f,0.f,0.f,0.f},{0.f,0.f,0.f,0.f},
                      {0.f,0.f,0.f,0.f},{0.f,0.f,0.f,0.f}};
    for (int kc = 0; kc < 16; ++kc) {
        const int k = kc * 32 + quad * 8;
        float4 y0 = *(const float4*)(yrow + k);
        float4 y1 = *(const float4*)(yrow + k + 4);
        float4 s0 = *(const float4*)&sc_sh[k], s1 = *(const float4*)&sc_sh[k + 4];
        float4 h0 = *(const float4*)&sh_sh[k], h1v = *(const float4*)&sh_sh[k + 4];
        float xs[8];
        xs[0] = fmaxf(y0.x * s0.x + h0.x, 0.f);
        xs[1] = fmaxf(y0.y * s0.y + h0.y, 0.f);
        xs[2] = fmaxf(y0.z * s0.z + h0.z, 0.f);
        xs[3] = fmaxf(y0.w * s0.w + h0.w, 0.f);
        xs[4] = fmaxf(y1.x * s1.x + h1v.x, 0.f);
        xs[5] = fmaxf(y1.y * s1.y + h1v.y, 0.f);
        xs[6] = fmaxf(y1.z * s1.z + h1v.z, 0.f);
        xs[7] = fmaxf(y1.w * s1.w + h1v.w, 0.f);
        short8 ahi, alo;
        split8(xs, ahi, alo);
        #pragma unroll
        for (int ntl = 0; ntl < 4; ++ntl) {
            const int col = (wave * 4 + ntl) * 16 + l15;
            const size_t colk = (size_t)col * DHID + k;
            short8 bh = *(const short8*)(W2hi + colk);
            short8 bl = *(const short8*)(W2lo + colk);
            acc[ntl] = __builtin_amdgcn_mfma_f32_16x16x32_bf16(alo, bh, acc[ntl], 0,0,0);
            acc[ntl] = __builtin_amdgcn_mfma_f32_16x16x32_bf16(ahi, bl, acc[ntl], 0,0,0);
            acc[ntl] = __builtin_amdgcn_mfma_f32_16x16x32_bf16(ahi, bh, acc[ntl], 0,0,0);
        }
    }
    float bias[4];
    #pragma unroll
    for (int ntl = 0; ntl < 4; ++ntl) bias[ntl] = b2[(wave * 4 + ntl) * 16 + l15];

    float zv[4][4];     // [reg][ntl]
    float sqp[4];
    #pragma unroll
    for (int reg = 0; reg < 4; ++reg) {
        float sq = 0.f;
        #pragma unroll
        for (int ntl = 0; ntl < 4; ++ntl) {
            zv[reg][ntl] = acc[ntl][reg] + bias[ntl];
            sq += zv[reg][ntl] * zv[reg][ntl];
        }
        sq += __shfl_xor(sq, 1); sq += __shfl_xor(sq, 2);
        sq += __shfl_xor(sq, 4); sq += __shfl_xor(sq, 8);
        sqp[reg] = sq;
        if (l15 == 0) sq_lds[wave][quad * 4 + reg] = sq;
    }
    __syncthreads();
    #pragma unroll
    for (int reg = 0; reg < 4; ++reg) {
        float tot = sqp[reg] + sq_lds[wave ^ 1][quad * 4 + reg];
        float inv = 1.0f / fmaxf(sqrtf(tot), 1e-12f);
        const int row = mtbase + quad * 4 + reg;
        const size_t ob = (size_t)row * DOUT;
        #pragma unroll
        for (int ntl = 0; ntl < 4; ++ntl) {
            const int col = (wave * 4 + ntl) * 16 + l15;
            float z = zv[reg][ntl] * inv;
            outz[ob + col] = z;
            Zb[ob + col] = bf16_rne(z * ZSCALE);
        }
    }
}

// ---- sim: psum_row = sum_cols exp2(Zb . Zb^T)  (diag included; subtracted
// in row_finalize). Wave: 64 rows (4 A-tiles, 64 VGPRs). 16 stages of 16
// cols; 3-buffer rotation, prefetch distance 2 (fully unrolled, constant
// indices). grid (32, NSPLIT) x 256 thr.
__global__ __launch_bounds__(256) void sim_mfma(
    const unsigned short* __restrict__ Zb, float* __restrict__ psum)
{
    const int t = threadIdx.x;
    const int wave = t >> 6, lane = t & 63;
    const int quad = lane >> 4, l15 = lane & 15;
    const int mbase = blockIdx.x * 256 + wave * 64;
    const int cs = blockIdx.y;
    const int cbase = cs * (N2 / NSPLIT);   // 256-col slice

    short8 a[4][4];
    #pragma unroll
    for (int at = 0; at < 4; ++at) {
        const short8* zra = (const short8*)(Zb + (size_t)(mbase + at * 16 + l15) * DOUT + quad * 8);
        #pragma unroll
        for (int kc = 0; kc < 4; ++kc) a[at][kc] = zra[kc * 4];
    }

    float rs[4][4];
    #pragma unroll
    for (int at = 0; at < 4; ++at)
        #pragma unroll
        for (int r = 0; r < 4; ++r) rs[at][r] = 0.f;

    // per-lane B base: stage s is at byte offset s*16*DOUT*2 from here
    const short8* bptr = (const short8*)(Zb + (size_t)(cbase + l15) * DOUT + quad * 8);
    short8 b[3][4];
    #pragma unroll
    for (int s = 0; s < 2; ++s)
        #pragma unroll
        for (int kc = 0; kc < 4; ++kc)
            b[s][kc] = bptr[s * 256 + kc * 4];   // 256 short8 = 16 rows of 128

    #pragma unroll
    for (int s = 0; s < 16; ++s) {
        if (s + 2 < 16) {
            #pragma unroll
            for (int kc = 0; kc < 4; ++kc)
                b[(s + 2) % 3][kc] = bptr[(s + 2) * 256 + kc * 4];
        }
        floatx4 acc[4] = {{0.f,0.f,0.f,0.f},{0.f,0.f,0.f,0.f},
                          {0.f,0.f,0.f,0.f},{0.f,0.f,0.f,0.f}};
        #pragma unroll
        for (int kc = 0; kc < 4; ++kc)
            #pragma unroll
            for (int at = 0; at < 4; ++at)
                acc[at] = __builtin_amdgcn_mfma_f32_16x16x32_bf16(
                    a[at][kc], b[s % 3][kc], acc[at], 0,0,0);
        #pragma unroll
        for (int at = 0; at < 4; ++at)
            #pragma unroll
            for (int r = 0; r < 4; ++r)
                rs[at][r] += exp2f(acc[at][r]);
    }

    #pragma unroll
    for (int at = 0; at < 4; ++at) {
        const int gi0 = mbase + at * 16 + quad * 4;
        #pragma unroll
        for (int r = 0; r < 4; ++r) {
            float s = rs[at][r];
            s += __shfl_xor(s, 1); s += __shfl_xor(s, 2);
            s += __shfl_xor(s, 4); s += __shfl_xor(s, 8);
            if (l15 == 0) psum[(size_t)cs * N2 + gi0 + r] = s;
        }
    }
}

// ---- per-row lse - pos, minus diag term; block-reduce -> atomic loss ------
__global__ __launch_bounds__(256) void row_finalize(
    const unsigned short* __restrict__ Zb, const float* __restrict__ psum,
    float* __restrict__ out)
{
    int i = blockIdx.x * 256 + threadIdx.x;
    float s = 0.f;
    #pragma unroll
    for (int cs = 0; cs < NSPLIT; ++cs) s += psum[(size_t)cs * N2 + i];
    int k = i & (NB - 1);
    const uint4* z1 = (const uint4*)(Zb + (size_t)k * DOUT);
    const uint4* z2 = (const uint4*)(Zb + (size_t)(k + NB) * DOUT);
    float d12 = 0.f, d11 = 0.f, d22 = 0.f;
    #pragma unroll
    for (int q = 0; q < 16; ++q) {
        uint4 a = z1[q], bqq = z2[q];
        const unsigned int aw[4] = {a.x, a.y, a.z, a.w};
        const unsigned int bw[4] = {bqq.x, bqq.y, bqq.z, bqq.w};
        #pragma unroll
        for (int c = 0; c < 4; ++c) {
            float alo = __uint_as_float(aw[c] << 16);
            float ahi = __uint_as_float(aw[c] & 0xffff0000u);
            float blo = __uint_as_float(bw[c] << 16);
            float bhi = __uint_as_float(bw[c] & 0xffff0000u);
            d12 += alo * blo + ahi * bhi;
            d11 += alo * alo + ahi * ahi;
            d22 += blo * blo + bhi * bhi;
        }
    }
    float dself = (i < NB) ? d11 : d22;
    // Zb is scaled: dot' = 2*log2(e)*dot  =>  2*dot = dot'*ln2; diag = exp2(dot')
    float rowval = logf(s - exp2f(dself)) - d12 * 0.69314718f;

    float r = rowval;
    r += __shfl_xor(r, 1);  r += __shfl_xor(r, 2);  r += __shfl_xor(r, 4);
    r += __shfl_xor(r, 8);  r += __shfl_xor(r, 16); r += __shfl_xor(r, 32);
    __shared__ float wsr[4];
    int lane = threadIdx.x & 63, w = threadIdx.x >> 6;
    if (lane == 0) wsr[w] = r;
    __syncthreads();
    if (threadIdx.x == 0)
        atomicAdd(out, (wsr[0] + wsr[1] + wsr[2] + wsr[3]) * (1.0f / N2));
}

extern "C" void kernel_launch(void* const* d_in, const int* in_sizes, int n_in,
                              void* d_out, int out_size, void* d_ws, size_t ws_size,
                              hipStream_t stream)
{
    const float* h1    = (const float*)d_in[0];
    const float* h2    = (const float*)d_in[1];
    const float* W1    = (const float*)d_in[2];
    const float* b1    = (const float*)d_in[3];
    const float* gamma = (const float*)d_in[4];
    const float* beta  = (const float*)d_in[5];
    const float* W2    = (const float*)d_in[6];
    const float* b2    = (const float*)d_in[7];
    float* out = (float*)d_out;

    float* ws      = (float*)d_ws;
    float* psumc   = ws;                            // 1024 f
    float* psqc    = psumc + 1024;                  // 1024 f
    unsigned short* W1hi = (unsigned short*)(psqc + 1024);  // 98304 us
    unsigned short* W1lo = W1hi + DHID * DIN;
    unsigned short* W2hi = W1lo + DHID * DIN;       // 65536 us
    unsigned short* W2lo = W2hi + DOUT * DHID;
    float* Y       = (float*)(W2lo + DOUT * DHID);  // 8192*512 = 4M f
    float* psum    = Y + (size_t)N2 * DHID;         // 32*8192 f
    unsigned short* Zb = (unsigned short*)(psum + (size_t)NSPLIT * N2); // 1M us
    // total ~19.3 MB

    hipMemsetAsync(psumc, 0, 2048 * sizeof(float), stream);  // psumc+psqc
    hipMemsetAsync(out, 0, sizeof(float), stream);           // loss accumulator

    convert_w   <<<dim3(160),       256, 0, stream>>>(W1, W2, W1hi, W1lo, W2hi, W2lo);
    gemm1_mfma  <<<dim3(64, 8),     256, 0, stream>>>(h1, h2, W1hi, W1lo, b1, Y, psumc, psqc);
    gemm2_mfma  <<<dim3(512),       128, 0, stream>>>(Y, W2hi, W2lo, psumc, psqc, gamma, beta, b2, Zb, out + 1);
    sim_mfma    <<<dim3(32, NSPLIT), 256, 0, stream>>>(Zb, psum);
    row_finalize<<<dim3(32),        256, 0, stream>>>(Zb, psum, out);
}